// Round 12
// baseline (3606.434 us; speedup 1.0000x reference)
//
#include <hip/hip_runtime.h>
#include <hip/hip_bf16.h>
#include <stdint.h>

#define G_ 4
#define E_ 16
#define C_ 2048
#define H_ 512
#define F_ 2048

typedef __attribute__((ext_vector_type(8))) short bf16x8;
typedef __attribute__((ext_vector_type(4))) float f32x4;
typedef uint32_t u32_glb __attribute__((address_space(1)));
typedef uint32_t u32_lds __attribute__((address_space(3)));

__device__ __forceinline__ ushort f2bf(float f){
  uint u = __float_as_uint(f);
  return (ushort)((u + 0x7FFFu + ((u >> 16) & 1u)) >> 16);  // RNE
}

__device__ __forceinline__ bf16x8 pack8(f32x4 a, f32x4 b){
  union { bf16x8 v; uint u[4]; } p;
  p.u[0] = (uint)f2bf(a[0]) | ((uint)f2bf(a[1]) << 16);
  p.u[1] = (uint)f2bf(a[2]) | ((uint)f2bf(a[3]) << 16);
  p.u[2] = (uint)f2bf(b[0]) | ((uint)f2bf(b[1]) << 16);
  p.u[3] = (uint)f2bf(b[2]) | ((uint)f2bf(b[3]) << 16);
  return p.v;
}

// fast GELU: t*sigmoid(2y), y = 0.79788456(t + 0.044715 t^3).
__device__ __forceinline__ f32x4 gelu4f(f32x4 v){
  f32x4 r;
  #pragma unroll
  for (int i = 0; i < 4; ++i){
    float t = v[i];
    float y = 0.7978845608f * t * (1.0f + 0.044715f * t * t);
    y = fminf(fmaxf(y, -9.0f), 9.0f);
    float z = __expf(-2.0f * y);
    r[i] = t * __builtin_amdgcn_rcpf(1.0f + z);
  }
  return r;
}

// transpose + fp32->bf16 convert: src [E][R][C] fp32 -> dst [E][C][R] bf16
__global__ void transpose_cvt(const float* __restrict__ src, ushort* __restrict__ dst,
                              int R, int C){
  __shared__ float tile[64][65];
  int c0 = blockIdx.x * 64, r0 = blockIdx.y * 64, e = blockIdx.z;
  int tx = threadIdx.x & 63, ty = threadIdx.x >> 6;   // 256 threads
  const float* s = src + (size_t)e * R * C;
  #pragma unroll
  for (int it = 0; it < 16; ++it){
    int row = ty + it * 4;
    tile[row][tx] = s[(size_t)(r0 + row) * C + (c0 + tx)];
  }
  __syncthreads();
  ushort* d = dst + (size_t)e * C * R;
  #pragma unroll
  for (int it = 0; it < 16; ++it){
    int row = ty + it * 4;
    d[(size_t)(c0 + row) * R + (r0 + tx)] = f2bf(tile[tx][row]);
  }
}

// ffn_fused9: R11 math/patterns exactly, restructured for 2 blocks/CU:
// LDS 68 KB (single-buffered weights), VGPR <= 128 via __launch_bounds__(512,4).
// W1: DMA single-buf, issued post-B_pa (G1 reads provably done).
// W2: T14 reg-stage - loads post-B_pa(t) for t+1, ds_write at t+1 start (post-B_buf).
__global__ __launch_bounds__(512, 4) void ffn_fused9(
    const float* __restrict__ x,      // [G][E][C][H] fp32
    const float* __restrict__ b1,     // [E][F] fp32
    const float* __restrict__ b2,     // [E][H] fp32
    const ushort* __restrict__ w1t,   // [E][F][H] bf16
    const ushort* __restrict__ w2t,   // [E][H][F] bf16
    float* __restrict__ out){         // [G][E][C][H] fp32
  __shared__ ushort sW1[32 * 512];    // 32KB [f-row][h], content XOR key=(row&7)<<4
  __shared__ ushort sW2[512 * 32];    // 32KB [h] 64B rows, 16B slot q^((h>>1)&3)
  __shared__ uchar  sPa[4096];        // [tok 64][f 32] bf16

  const int tid  = threadIdx.x;
  const int lane = tid & 63;
  const int wv   = tid >> 6;          // 0..7
  const int l15  = lane & 15;
  const int lg   = lane >> 4;         // 0..3
  const int tg   = wv >> 1;           // token group (16 tokens)
  const int hh   = wv & 1;            // f-half (G1) / h-half (G2)

  // XCD-aware bijective swizzle: 2048 blocks = 8 XCDs x 256
  const int bid  = (blockIdx.x & 7) * 256 + (blockIdx.x >> 3);
  const int e    = bid >> 7;          // 128 blocks/expert
  const int mb   = bid & 127;
  const int n0   = mb * 64;
  const int g    = n0 >> 11;
  const int c0   = n0 & (C_ - 1);

  // X fragments: lane's token = c0 + tg*16 + l15, full K; k = kk*32 + lg*8 + j
  const float* xr = x + ((size_t)(g * E_ + e) * C_ + (c0 + tg * 16 + l15)) * H_;
  bf16x8 xf[16];
  #pragma unroll
  for (int kk = 0; kk < 16; ++kk){
    f32x4 fa = *(const f32x4*)(xr + kk * 32 + lg * 8);
    f32x4 fb = *(const f32x4*)(xr + kk * 32 + lg * 8 + 4);
    xf[kk] = pack8(fa, fb);
  }

  f32x4 acc2[16];                     // 16 tok x 256 h (hh half) -> 64 VGPR, FINAL
  #pragma unroll
  for (int ht = 0; ht < 16; ++ht) acc2[ht] = (f32x4){0.f, 0.f, 0.f, 0.f};

  const ushort* w1e = w1t + (size_t)e * F_ * H_;
  const ushort* w2e = w2t + (size_t)e * H_ * F_;
  const float*  b1e = b1  + (size_t)e * F_ + hh * 16 + lg * 4;
  uint4 w2r[4];                       // W2 staging regs (16 VGPR)

  // W1 DMA: 4 instr/wave, rows wv+8it, linear dest, pre-swizzled source
  #define STAGE_W1(F0)                                                           \
    { _Pragma("unroll")                                                          \
      for (int it = 0; it < 4; ++it){                                            \
        int row = wv + it * 8;                                                   \
        const ushort* gsrc = w1e + (size_t)((F0) + row) * H_                     \
                           + (((lane * 16) ^ ((row & 7) << 4)) >> 1);            \
        __builtin_amdgcn_global_load_lds((const u32_glb*)(uintptr_t)gsrc,        \
            (u32_lds*)(uintptr_t)(&sW1[row * 512]), 16, 0, 0);                   \
      } }
  // W2 reg-stage: issue 4 b128 loads (linear source)
  #define STAGE_W2_ISSUE(F0)                                                     \
    { _Pragma("unroll")                                                          \
      for (int i = 0; i < 4; ++i){                                               \
        int seg = i * 512 + tid;                                                 \
        w2r[i] = *(const uint4*)(w2e + (size_t)(seg >> 2) * F_ + (F0) + (seg & 3) * 8); \
      } }
  // W2 write: slot-XOR dest (matches G2 read), conflict-free
  #define STAGE_W2_WRITE()                                                       \
    { _Pragma("unroll")                                                          \
      for (int i = 0; i < 4; ++i){                                               \
        int seg = i * 512 + tid;                                                 \
        int h = seg >> 2, q = seg & 3;                                           \
        *(uint4*)((char*)sW2 + h * 64 + 16 * (q ^ ((h >> 1) & 3))) = w2r[i];     \
      } }

  // ---- prologue: stage chunk 0 ----
  STAGE_W2_ISSUE(0)
  STAGE_W1(0)
  asm volatile("s_waitcnt vmcnt(0)" ::: "memory");
  asm volatile("s_waitcnt lgkmcnt(0)" ::: "memory");
  __builtin_amdgcn_s_barrier();

  const int r1   = hh * 16 + l15;     // G1 A-row (f within chunk)
  const int sw1  = (r1 & 7) << 4;
  const char* paw = (const char*)sPa + (tg * 16 + l15) * 64;

  for (int t = 0; t < 64; ++t){
    // ---- sW2 <- W2(t) from regs (G2(t-1) reads finished at B_buf(t-1)) ----
    STAGE_W2_WRITE()

    // ---- G1: 16 MFMA, two independent chains (reads sW1 = W1(t)) ----
    f32x4 a1a = (f32x4){0.f,0.f,0.f,0.f};
    f32x4 a1b = (f32x4){0.f,0.f,0.f,0.f};
    {
      const char* rb = (const char*)sW1 + r1 * 1024;
      __builtin_amdgcn_s_setprio(1);
      #pragma unroll
      for (int kk = 0; kk < 16; ++kk){
        bf16x8 afr = *(const bf16x8*)(rb + ((kk * 64 + lg * 16) ^ sw1));
        if (kk & 1) a1b = __builtin_amdgcn_mfma_f32_16x16x32_bf16(afr, xf[kk], a1b, 0, 0, 0);
        else        a1a = __builtin_amdgcn_mfma_f32_16x16x32_bf16(afr, xf[kk], a1a, 0, 0, 0);
      }
      __builtin_amdgcn_s_setprio(0);
    }

    // ---- bias + GELU (lane: f = t*32 + hh*16 + lg*4 + i, tok = tg*16 + l15) ----
    {
      f32x4 b1v = *(const f32x4*)(b1e + t * 32);
      f32x4 gv = gelu4f((a1a + a1b) + b1v);
      uint2 pw;
      pw.x = (uint)f2bf(gv[0]) | ((uint)f2bf(gv[1]) << 16);
      pw.y = (uint)f2bf(gv[2]) | ((uint)f2bf(gv[3]) << 16);
      *(uint2*)((char*)paw + hh * 32 + lg * 8) = pw;
    }
    asm volatile("s_waitcnt lgkmcnt(0)" ::: "memory");
    __builtin_amdgcn_s_barrier();                      // B_pa: G1 reads done, pa+sW2 visible

    // ---- prefetch t+1: W1 DMA into sW1 (now safe), W2 global loads ----
    if (t < 63){
      STAGE_W1((t + 1) * 32)
      STAGE_W2_ISSUE((t + 1) * 32)
    }

    // ---- G2: A = pa (b128, k = lg*8+j = f), B = W2 rows, 16 indep accs ----
    {
      bf16x8 paf = *(const bf16x8*)(paw + lg * 16);
      const char* wb = (const char*)sW2;
      __builtin_amdgcn_s_setprio(1);
      #pragma unroll
      for (int ht = 0; ht < 16; ++ht){
        int h = hh * 256 + ht * 16 + l15;
        bf16x8 bfr = *(const bf16x8*)(wb + h * 64 + 16 * (lg ^ ((h >> 1) & 3)));
        acc2[ht] = __builtin_amdgcn_mfma_f32_16x16x32_bf16(paf, bfr, acc2[ht], 0, 0, 0);
      }
      __builtin_amdgcn_s_setprio(0);
    }
    asm volatile("s_waitcnt vmcnt(0)" ::: "memory");   // W1(t+1) landed, w2r(t+1) loaded
    asm volatile("s_waitcnt lgkmcnt(0)" ::: "memory");
    __builtin_amdgcn_s_barrier();                      // B_buf: G2 reads done
  }

  // ---- epilogue: D2 col = l15 (h), row = lg*4+i (token) ----
  const size_t ob = (size_t)(g * E_ + e) * C_ + c0 + tg * 16 + lg * 4;
  #pragma unroll
  for (int ht = 0; ht < 16; ++ht){
    const int h  = hh * 256 + ht * 16 + l15;
    const float bb = b2[(size_t)e * H_ + h];
    #pragma unroll
    for (int i = 0; i < 4; ++i)
      out[(ob + i) * H_ + h] = acc2[ht][i] + bb;
  }
  #undef STAGE_W1
  #undef STAGE_W2_ISSUE
  #undef STAGE_W2_WRITE
}

extern "C" void kernel_launch(void* const* d_in, const int* in_sizes, int n_in,
                              void* d_out, int out_size, void* d_ws, size_t ws_size,
                              hipStream_t stream){
  const float *x = nullptr, *b1 = nullptr, *b2 = nullptr;
  const float* w12[2] = {nullptr, nullptr}; int nw = 0;
  for (int i = 0; i < n_in; ++i){
    long s = (long)in_sizes[i];
    if      (s == (long)G_ * E_ * C_ * H_) x = (const float*)d_in[i];
    else if (s == (long)E_ * H_ * F_) { if (nw < 2) w12[nw++] = (const float*)d_in[i]; }
    else if (s == (long)E_ * F_) b1 = (const float*)d_in[i];
    else if (s == (long)E_ * H_) b2 = (const float*)d_in[i];
  }
  const float* w1 = w12[0];
  const float* w2 = w12[1];
  if (!x || !w1 || !w2 || !b1 || !b2){
    x  = (const float*)d_in[0];
    w1 = (const float*)d_in[1];
    b1 = (const float*)d_in[2];
    w2 = (const float*)d_in[3];
    b2 = (const float*)d_in[4];
  }

  ushort* w1t = (ushort*)d_ws;                       // [E][F][H] bf16
  ushort* w2t = w1t + (size_t)E_ * F_ * H_;          // [E][H][F] bf16

  transpose_cvt<<<dim3(F_ / 64, H_ / 64, E_), dim3(256), 0, stream>>>(w1, w1t, H_, F_);
  transpose_cvt<<<dim3(H_ / 64, F_ / 64, E_), dim3(256), 0, stream>>>(w2, w2t, F_, H_);

  ffn_fused9<<<dim3(2048), dim3(512), 0, stream>>>(x, b1, b2, w1t, w2t, (float*)d_out);
}

// Round 13
// 1249.584 us; speedup vs baseline: 2.8861x; 2.8861x over previous
//
#include <hip/hip_runtime.h>
#include <hip/hip_bf16.h>
#include <stdint.h>

#define G_ 4
#define E_ 16
#define C_ 2048
#define H_ 512
#define F_ 2048

typedef __attribute__((ext_vector_type(8))) short bf16x8;
typedef __attribute__((ext_vector_type(4))) float f32x4;
typedef uint32_t u32_glb __attribute__((address_space(1)));
typedef uint32_t u32_lds __attribute__((address_space(3)));

__device__ __forceinline__ ushort f2bf(float f){
  uint u = __float_as_uint(f);
  return (ushort)((u + 0x7FFFu + ((u >> 16) & 1u)) >> 16);  // RNE
}

__device__ __forceinline__ bf16x8 pack8(f32x4 a, f32x4 b){
  union { bf16x8 v; uint u[4]; } p;
  p.u[0] = (uint)f2bf(a[0]) | ((uint)f2bf(a[1]) << 16);
  p.u[1] = (uint)f2bf(a[2]) | ((uint)f2bf(a[3]) << 16);
  p.u[2] = (uint)f2bf(b[0]) | ((uint)f2bf(b[1]) << 16);
  p.u[3] = (uint)f2bf(b[2]) | ((uint)f2bf(b[3]) << 16);
  return p.v;
}

// fast GELU: t*sigmoid(2y), y = 0.79788456(t + 0.044715 t^3).
__device__ __forceinline__ f32x4 gelu4f(f32x4 v){
  f32x4 r;
  #pragma unroll
  for (int i = 0; i < 4; ++i){
    float t = v[i];
    float y = 0.7978845608f * t * (1.0f + 0.044715f * t * t);
    y = fminf(fmaxf(y, -9.0f), 9.0f);
    float z = __expf(-2.0f * y);
    r[i] = t * __builtin_amdgcn_rcpf(1.0f + z);
  }
  return r;
}

// transpose + fp32->bf16 convert: src [E][R][C] fp32 -> dst [E][C][R] bf16
__global__ void transpose_cvt(const float* __restrict__ src, ushort* __restrict__ dst,
                              int R, int C){
  __shared__ float tile[64][65];
  int c0 = blockIdx.x * 64, r0 = blockIdx.y * 64, e = blockIdx.z;
  int tx = threadIdx.x & 63, ty = threadIdx.x >> 6;   // 256 threads
  const float* s = src + (size_t)e * R * C;
  #pragma unroll
  for (int it = 0; it < 16; ++it){
    int row = ty + it * 4;
    tile[row][tx] = s[(size_t)(r0 + row) * C + (c0 + tx)];
  }
  __syncthreads();
  ushort* d = dst + (size_t)e * C * R;
  #pragma unroll
  for (int it = 0; it < 16; ++it){
    int row = ty + it * 4;
    d[(size_t)(c0 + row) * R + (r0 + tx)] = f2bf(tile[tx][row]);
  }
}

// ffn_fused10: R11 dataflow, K-split G1 to fit 128 regs -> 2 blocks/CU.
// 8 waves = 4 tg(16 tok) x 2 s. G1: wave s computes ALL 32 f over K-half s
// (xf[8]=32 VGPR, 16 b128 reads, 16 MFMA, 2 indep chains). Exchange: publish
// partner's GELU half only (1 f32x4). GELU on own half -> pa. G2: h-half s,
// acc2[16] in AGPR. LDS 76 KB single-buffered weights, all staging via DMA.
__global__ __launch_bounds__(512, 4) void ffn_fused10(
    const float* __restrict__ x,      // [G][E][C][H] fp32
    const float* __restrict__ b1,     // [E][F] fp32
    const float* __restrict__ b2,     // [E][H] fp32
    const ushort* __restrict__ w1t,   // [E][F][H] bf16
    const ushort* __restrict__ w2t,   // [E][H][F] bf16
    float* __restrict__ out){         // [G][E][C][H] fp32
  __shared__ ushort sW1[32 * 512];    // 32KB [f-row][h], content XOR key=(row&7)<<4
  __shared__ ushort sW2[512 * 32];    // 32KB [h] 64B rows, 16B slot q^((h>>1)&3)
  __shared__ f32x4  sEx[4][2][64];    //  8KB partner-half partials
  __shared__ uchar  sPa[4096];        //  4KB [tok 64][f 32] bf16

  const int tid  = threadIdx.x;
  const int lane = tid & 63;
  const int wv   = tid >> 6;          // 0..7
  const int l15  = lane & 15;
  const int lg   = lane >> 4;         // 0..3
  const int tg   = wv >> 1;           // token group (16 tokens)
  const int s    = wv & 1;            // K-half (G1) / GELU f-half / h-half (G2)

  // XCD-aware bijective swizzle: 2048 blocks = 8 XCDs x 256
  const int bid  = (blockIdx.x & 7) * 256 + (blockIdx.x >> 3);
  const int e    = bid >> 7;          // 128 blocks/expert
  const int mb   = bid & 127;
  const int n0   = mb * 64;
  const int g    = n0 >> 11;
  const int c0   = n0 & (C_ - 1);

  // X fragments, own K-half only: k = s*256 + kk*32 + lg*8 + j  (32 VGPR)
  const float* xr = x + ((size_t)(g * E_ + e) * C_ + (c0 + tg * 16 + l15)) * H_ + s * 256;
  bf16x8 xf[8];
  #pragma unroll
  for (int kk = 0; kk < 8; ++kk){
    f32x4 fa = *(const f32x4*)(xr + kk * 32 + lg * 8);
    f32x4 fb = *(const f32x4*)(xr + kk * 32 + lg * 8 + 4);
    xf[kk] = pack8(fa, fb);
  }

  f32x4 acc2[16];                     // 16 tok x 256 h -> 64 regs (AGPR), FINAL
  #pragma unroll
  for (int ht = 0; ht < 16; ++ht) acc2[ht] = (f32x4){0.f, 0.f, 0.f, 0.f};

  const ushort* w1e = w1t + (size_t)e * F_ * H_;
  const ushort* w2e = w2t + (size_t)e * H_ * F_;
  const float*  b1e = b1  + (size_t)e * F_ + s * 16 + lg * 4;

  #define STAGE_W1(F0)                                                           \
    { _Pragma("unroll")                                                          \
      for (int it = 0; it < 4; ++it){                                            \
        int row = wv + it * 8;                                                   \
        const ushort* gsrc = w1e + (size_t)((F0) + row) * H_                     \
                           + (((lane * 16) ^ ((row & 7) << 4)) >> 1);            \
        __builtin_amdgcn_global_load_lds((const u32_glb*)(uintptr_t)gsrc,        \
            (u32_lds*)(uintptr_t)(&sW1[row * 512]), 16, 0, 0);                   \
      } }
  #define STAGE_W2(F0)                                                           \
    { _Pragma("unroll")                                                          \
      for (int it = 0; it < 4; ++it){                                            \
        int hb = (wv * 4 + it) * 16;                                             \
        int h  = hb + (lane >> 2);                                               \
        int q  = lane & 3;                                                       \
        const ushort* gsrc = w2e + (size_t)h * F_ + (F0)                         \
                           + ((q ^ ((h >> 1) & 3)) * 8);                         \
        __builtin_amdgcn_global_load_lds((const u32_glb*)(uintptr_t)gsrc,        \
            (u32_lds*)(uintptr_t)(&sW2[hb * 32]), 16, 0, 0);                     \
      } }

  // ---- prologue: stage chunk 0 ----
  STAGE_W1(0)
  STAGE_W2(0)
  asm volatile("s_waitcnt vmcnt(0)" ::: "memory");
  asm volatile("s_waitcnt lgkmcnt(0)" ::: "memory");
  __builtin_amdgcn_s_barrier();

  const int sw1   = (l15 & 7) << 4;   // G1 row swizzle key (rows l15 and 16+l15)
  const char* paw = (const char*)sPa + (tg * 16 + l15) * 64;

  for (int t = 0; t < 64; ++t){
    // ---- G1 (K-half s, all 32 f): 2 indep chains, 16 b128, 16 MFMA ----
    f32x4 a1lo = (f32x4){0.f,0.f,0.f,0.f};   // f 0..15
    f32x4 a1hi = (f32x4){0.f,0.f,0.f,0.f};   // f 16..31
    {
      const char* rb0 = (const char*)sW1 + l15 * 1024;
      const char* rb1 = rb0 + 16 * 1024;
      __builtin_amdgcn_s_setprio(1);
      #pragma unroll
      for (int kk = 0; kk < 8; ++kk){
        const int kb = (((s * 8 + kk) * 64 + lg * 16) ^ sw1);
        bf16x8 a0 = *(const bf16x8*)(rb0 + kb);
        a1lo = __builtin_amdgcn_mfma_f32_16x16x32_bf16(a0, xf[kk], a1lo, 0, 0, 0);
        bf16x8 a1 = *(const bf16x8*)(rb1 + kb);
        a1hi = __builtin_amdgcn_mfma_f32_16x16x32_bf16(a1, xf[kk], a1hi, 0, 0, 0);
      }
      __builtin_amdgcn_s_setprio(0);
    }

    // ---- exchange: publish the tile the PARTNER will GELU ----
    sEx[tg][s][lane] = s ? a1lo : a1hi;
    asm volatile("s_waitcnt lgkmcnt(0)" ::: "memory");
    __builtin_amdgcn_s_barrier();                      // B_ex: G1 reads + sEx done

    if (t < 63) STAGE_W1((t + 1) * 32)                 // sW1 free; lands by B_buf

    // ---- sum + bias + GELU (own f-half s) -> pa ----
    {
      f32x4 own  = s ? a1hi : a1lo;
      f32x4 full = own + sEx[tg][1 - s][lane];
      f32x4 b1v  = *(const f32x4*)(b1e + t * 32);
      f32x4 gv   = gelu4f(full + b1v);                 // f = t*32 + s*16 + lg*4 + i
      uint2 pw;
      pw.x = (uint)f2bf(gv[0]) | ((uint)f2bf(gv[1]) << 16);
      pw.y = (uint)f2bf(gv[2]) | ((uint)f2bf(gv[3]) << 16);
      *(uint2*)((char*)paw + s * 32 + lg * 8) = pw;
    }
    if (t < 63) { asm volatile("s_waitcnt vmcnt(4)" ::: "memory"); }  // W2(t) landed
    else        { asm volatile("s_waitcnt vmcnt(0)" ::: "memory"); }
    asm volatile("s_waitcnt lgkmcnt(0)" ::: "memory");
    __builtin_amdgcn_s_barrier();                      // B_pa

    // ---- G2: A = pa b128 (k = lg*8+j = f), B = sW2 rows, 16 indep accs ----
    {
      bf16x8 paf = *(const bf16x8*)(paw + lg * 16);
      const char* wb = (const char*)sW2;
      __builtin_amdgcn_s_setprio(1);
      #pragma unroll
      for (int ht = 0; ht < 16; ++ht){
        int h = s * 256 + ht * 16 + l15;
        bf16x8 bfr = *(const bf16x8*)(wb + h * 64 + 16 * (lg ^ ((h >> 1) & 3)));
        acc2[ht] = __builtin_amdgcn_mfma_f32_16x16x32_bf16(paf, bfr, acc2[ht], 0, 0, 0);
      }
      __builtin_amdgcn_s_setprio(0);
    }
    asm volatile("s_waitcnt vmcnt(0)" ::: "memory");   // W1(t+1) landed
    asm volatile("s_waitcnt lgkmcnt(0)" ::: "memory");
    __builtin_amdgcn_s_barrier();                      // B_buf: G2+pa reads done
    if (t < 63) STAGE_W2((t + 1) * 32)                 // sW2 free; retired at B_pa(t+1)
  }

  // ---- epilogue: D2 col = l15 (h), row = lg*4+i (token) ----
  const size_t ob = (size_t)(g * E_ + e) * C_ + c0 + tg * 16 + lg * 4;
  #pragma unroll
  for (int ht = 0; ht < 16; ++ht){
    const int h  = s * 256 + ht * 16 + l15;
    const float bb = b2[(size_t)e * H_ + h];
    #pragma unroll
    for (int i = 0; i < 4; ++i)
      out[(ob + i) * H_ + h] = acc2[ht][i] + bb;
  }
  #undef STAGE_W1
  #undef STAGE_W2
}

extern "C" void kernel_launch(void* const* d_in, const int* in_sizes, int n_in,
                              void* d_out, int out_size, void* d_ws, size_t ws_size,
                              hipStream_t stream){
  const float *x = nullptr, *b1 = nullptr, *b2 = nullptr;
  const float* w12[2] = {nullptr, nullptr}; int nw = 0;
  for (int i = 0; i < n_in; ++i){
    long sz = (long)in_sizes[i];
    if      (sz == (long)G_ * E_ * C_ * H_) x = (const float*)d_in[i];
    else if (sz == (long)E_ * H_ * F_) { if (nw < 2) w12[nw++] = (const float*)d_in[i]; }
    else if (sz == (long)E_ * F_) b1 = (const float*)d_in[i];
    else if (sz == (long)E_ * H_) b2 = (const float*)d_in[i];
  }
  const float* w1 = w12[0];
  const float* w2 = w12[1];
  if (!x || !w1 || !w2 || !b1 || !b2){
    x  = (const float*)d_in[0];
    w1 = (const float*)d_in[1];
    b1 = (const float*)d_in[2];
    w2 = (const float*)d_in[3];
    b2 = (const float*)d_in[4];
  }

  ushort* w1t = (ushort*)d_ws;                       // [E][F][H] bf16
  ushort* w2t = w1t + (size_t)E_ * F_ * H_;          // [E][H][F] bf16

  transpose_cvt<<<dim3(F_ / 64, H_ / 64, E_), dim3(256), 0, stream>>>(w1, w1t, H_, F_);
  transpose_cvt<<<dim3(H_ / 64, F_ / 64, E_), dim3(256), 0, stream>>>(w2, w2t, F_, H_);

  ffn_fused10<<<dim3(2048), dim3(512), 0, stream>>>(x, b1, b2, w1t, w2t, (float*)d_out);
}

// Round 14
// 1148.734 us; speedup vs baseline: 3.1395x; 1.0878x over previous
//
#include <hip/hip_runtime.h>
#include <hip/hip_bf16.h>
#include <stdint.h>

#define G_ 4
#define E_ 16
#define C_ 2048
#define H_ 512
#define F_ 2048

typedef __attribute__((ext_vector_type(8))) short bf16x8;
typedef __attribute__((ext_vector_type(4))) float f32x4;
typedef uint32_t u32_glb __attribute__((address_space(1)));
typedef uint32_t u32_lds __attribute__((address_space(3)));

__device__ __forceinline__ ushort f2bf(float f){
  uint u = __float_as_uint(f);
  return (ushort)((u + 0x7FFFu + ((u >> 16) & 1u)) >> 16);  // RNE
}

__device__ __forceinline__ bf16x8 pack8(f32x4 a, f32x4 b){
  union { bf16x8 v; uint u[4]; } p;
  p.u[0] = (uint)f2bf(a[0]) | ((uint)f2bf(a[1]) << 16);
  p.u[1] = (uint)f2bf(a[2]) | ((uint)f2bf(a[3]) << 16);
  p.u[2] = (uint)f2bf(b[0]) | ((uint)f2bf(b[1]) << 16);
  p.u[3] = (uint)f2bf(b[2]) | ((uint)f2bf(b[3]) << 16);
  return p.v;
}

// fast GELU (R10-validated: absmax 1.95e-3 same as exact-erf version)
__device__ __forceinline__ float geluf(float t){
  float y = 0.7978845608f * t * (1.0f + 0.044715f * t * t);
  y = fminf(fmaxf(y, -9.0f), 9.0f);
  float z = __expf(-2.0f * y);
  return t * __builtin_amdgcn_rcpf(1.0f + z);
}

// transpose + fp32->bf16 convert: src [E][R][C] fp32 -> dst [E][C][R] bf16
__global__ void transpose_cvt(const float* __restrict__ src, ushort* __restrict__ dst,
                              int R, int C){
  __shared__ float tile[64][65];
  int c0 = blockIdx.x * 64, r0 = blockIdx.y * 64, e = blockIdx.z;
  int tx = threadIdx.x & 63, ty = threadIdx.x >> 6;   // 256 threads
  const float* s = src + (size_t)e * R * C;
  #pragma unroll
  for (int it = 0; it < 16; ++it){
    int row = ty + it * 4;
    tile[row][tx] = s[(size_t)(r0 + row) * C + (c0 + tx)];
  }
  __syncthreads();
  ushort* d = dst + (size_t)e * C * R;
  #pragma unroll
  for (int it = 0; it < 16; ++it){
    int row = ty + it * 4;
    d[(size_t)(c0 + row) * R + (r0 + tx)] = f2bf(tile[tx][row]);
  }
}

// ========== GEMM1+GELU: h1a[8192][2048] = gelu(X_e[8192][512] @ w1t_e^T + b1) ==========
// m97 structure: 128x128 tile, BK=32, 256 thr / 4 waves (2x2), 4x4 16x16x32 frags/wave.
// A (X fp32) reg-staged with bf16 convert; B (w1t bf16) via global_load_lds.
__global__ __launch_bounds__(256, 3) void gemm1_gelu(
    const float* __restrict__ x,      // [G][E][C][H] fp32
    const float* __restrict__ b1,     // [E][F]
    const ushort* __restrict__ w1t,   // [E][F][H] bf16
    ushort* __restrict__ h1a,         // [8192][2048] bf16 (slab)
    int e){
  __shared__ ushort sA[2][128 * 32];  // [m-row][k], 64B rows
  __shared__ ushort sB[2][128 * 32];  // [n-row(f)][k]
  const int tid  = threadIdx.x;
  const int lane = tid & 63;
  const int wv   = tid >> 6;
  const int l15  = lane & 15;
  const int lg   = lane >> 4;
  const int wm   = wv >> 1;           // wave M-half
  const int wn   = wv & 1;            // wave N-half
  const int m0   = blockIdx.x * 128;
  const int n0   = blockIdx.y * 128;

  const ushort* w1e = w1t + (size_t)e * F_ * H_;
  f32x4 acc[4][4];
  #pragma unroll
  for (int a = 0; a < 4; ++a)
    #pragma unroll
    for (int b = 0; b < 4; ++b) acc[a][b] = (f32x4){0.f,0.f,0.f,0.f};
  f32x4 ar[4];                        // A stage regs (16 floats/thread)

  // A: thread t covers row m0+(t>>1), 16 floats at k-half (t&1)
  const int arow = tid >> 1, ahf = tid & 1;
  const int an   = m0 + arow;
  const size_t agrow = ((size_t)(an >> 11) * 16 + e) * 2048 + (an & 2047);
  const float* asrc = x + agrow * 512 + ahf * 16;

  #define G1_LOAD_A(KK) {                                                        \
    const float* p = asrc + (KK) * 32;                                           \
    ar[0] = *(const f32x4*)p;      ar[1] = *(const f32x4*)(p + 4);               \
    ar[2] = *(const f32x4*)(p + 8); ar[3] = *(const f32x4*)(p + 12); }
  #define G1_WRITE_A(NB) {                                                       \
    ushort* d = &sA[NB][arow * 32 + ahf * 16];                                   \
    *(bf16x8*)d       = pack8(ar[0], ar[1]);                                     \
    *(bf16x8*)(d + 8) = pack8(ar[2], ar[3]); }
  #define G1_STAGE_B(KK, NB) {                                                   \
    _Pragma("unroll")                                                            \
    for (int i = 0; i < 2; ++i){                                                 \
      const ushort* gs = w1e + (size_t)(n0 + wv * 16 + i * 64 + (lane >> 2)) * H_\
                       + (KK) * 32 + (lane & 3) * 8;                             \
      __builtin_amdgcn_global_load_lds((const u32_glb*)(uintptr_t)gs,            \
          (u32_lds*)(uintptr_t)(&sB[NB][(wv * 16 + i * 64) * 32]), 16, 0, 0);    \
    } }

  G1_LOAD_A(0) G1_STAGE_B(0, 0) G1_WRITE_A(0)
  __syncthreads();

  for (int kk = 0; kk < 16; ++kk){
    const int cur = kk & 1, nxt = cur ^ 1;
    if (kk < 15){ G1_LOAD_A(kk + 1) G1_STAGE_B(kk + 1, nxt) }
    // compute: 8 ds_read_b128 + 16 MFMA (m97 ratio)
    bf16x8 af[4], bfr[4];
    #pragma unroll
    for (int mf = 0; mf < 4; ++mf)
      af[mf] = *(const bf16x8*)&sA[cur][(wm * 64 + mf * 16 + l15) * 32 + lg * 8];
    #pragma unroll
    for (int nf = 0; nf < 4; ++nf)
      bfr[nf] = *(const bf16x8*)&sB[cur][(wn * 64 + nf * 16 + l15) * 32 + lg * 8];
    __builtin_amdgcn_s_setprio(1);
    #pragma unroll
    for (int mf = 0; mf < 4; ++mf)
      #pragma unroll
      for (int nf = 0; nf < 4; ++nf)
        acc[mf][nf] = __builtin_amdgcn_mfma_f32_16x16x32_bf16(af[mf], bfr[nf], acc[mf][nf], 0, 0, 0);
    __builtin_amdgcn_s_setprio(0);
    if (kk < 15){ G1_WRITE_A(nxt) }
    __syncthreads();                  // drains vmcnt (B DMA landed) + lgkm
  }

  // epilogue: +b1, GELU, bf16 -> h1a. D: col=l15 (n), row=lg*4+i (m)
  #pragma unroll
  for (int nf = 0; nf < 4; ++nf){
    const int f  = n0 + wn * 64 + nf * 16 + l15;
    const float bb = b1[e * F_ + f];
    #pragma unroll
    for (int mf = 0; mf < 4; ++mf){
      const int m = m0 + wm * 64 + mf * 16 + lg * 4;
      #pragma unroll
      for (int i = 0; i < 4; ++i)
        h1a[(size_t)(m + i) * F_ + f] = f2bf(geluf(acc[mf][nf][i] + bb));
    }
  }
  #undef G1_LOAD_A
  #undef G1_WRITE_A
  #undef G1_STAGE_B
}

// ========== GEMM2: out_e[8192][512] = h1a[8192][2048] @ w2t_e^T + b2 ==========
// Same m97 structure; both operands bf16 via global_load_lds. z selects expert pair member.
__global__ __launch_bounds__(256, 3) void gemm2(
    const ushort* __restrict__ h1a,   // [2][8192][2048] bf16 (two slabs)
    const float* __restrict__ b2,     // [E][H]
    const ushort* __restrict__ w2t,   // [E][H][F] bf16
    float* __restrict__ out,          // [G][E][C][H] fp32
    int e0){
  __shared__ ushort sA[2][128 * 32];
  __shared__ ushort sB[2][128 * 32];
  const int tid  = threadIdx.x;
  const int lane = tid & 63;
  const int wv   = tid >> 6;
  const int l15  = lane & 15;
  const int lg   = lane >> 4;
  const int wm   = wv >> 1;
  const int wn   = wv & 1;
  const int m0   = blockIdx.x * 128;
  const int n0   = blockIdx.y * 128;  // h base (N=512)
  const int z    = blockIdx.z;
  const int e    = e0 + z;

  const ushort* ha  = h1a + (size_t)z * 8192 * F_;
  const ushort* w2e = w2t + (size_t)e * H_ * F_;

  f32x4 acc[4][4];
  #pragma unroll
  for (int a = 0; a < 4; ++a)
    #pragma unroll
    for (int b = 0; b < 4; ++b) acc[a][b] = (f32x4){0.f,0.f,0.f,0.f};

  #define G2_STAGE(KK, NB)  {                                                    \
    _Pragma("unroll")                                                            \
    for (int i = 0; i < 2; ++i){                                                 \
      const ushort* ga = ha + (size_t)(m0 + wv * 16 + i * 64 + (lane >> 2)) * F_ \
                       + (KK) * 32 + (lane & 3) * 8;                             \
      __builtin_amdgcn_global_load_lds((const u32_glb*)(uintptr_t)ga,            \
          (u32_lds*)(uintptr_t)(&sA[NB][(wv * 16 + i * 64) * 32]), 16, 0, 0);    \
      const ushort* gb = w2e + (size_t)(n0 + wv * 16 + i * 64 + (lane >> 2)) * F_\
                       + (KK) * 32 + (lane & 3) * 8;                             \
      __builtin_amdgcn_global_load_lds((const u32_glb*)(uintptr_t)gb,            \
          (u32_lds*)(uintptr_t)(&sB[NB][(wv * 16 + i * 64) * 32]), 16, 0, 0);    \
    } }

  G2_STAGE(0, 0)
  __syncthreads();

  for (int kk = 0; kk < 64; ++kk){
    const int cur = kk & 1, nxt = cur ^ 1;
    if (kk < 63){ G2_STAGE(kk + 1, nxt) }
    bf16x8 af[4], bfr[4];
    #pragma unroll
    for (int mf = 0; mf < 4; ++mf)
      af[mf] = *(const bf16x8*)&sA[cur][(wm * 64 + mf * 16 + l15) * 32 + lg * 8];
    #pragma unroll
    for (int nf = 0; nf < 4; ++nf)
      bfr[nf] = *(const bf16x8*)&sB[cur][(wn * 64 + nf * 16 + l15) * 32 + lg * 8];
    __builtin_amdgcn_s_setprio(1);
    #pragma unroll
    for (int mf = 0; mf < 4; ++mf)
      #pragma unroll
      for (int nf = 0; nf < 4; ++nf)
        acc[mf][nf] = __builtin_amdgcn_mfma_f32_16x16x32_bf16(af[mf], bfr[nf], acc[mf][nf], 0, 0, 0);
    __builtin_amdgcn_s_setprio(0);
    __syncthreads();
  }

  // epilogue: +b2, fp32 store to out (g-interleaved rows)
  #pragma unroll
  for (int nf = 0; nf < 4; ++nf){
    const int h  = n0 + wn * 64 + nf * 16 + l15;
    const float bb = b2[e * H_ + h];
    #pragma unroll
    for (int mf = 0; mf < 4; ++mf){
      const int m = m0 + wm * 64 + mf * 16 + lg * 4;
      #pragma unroll
      for (int i = 0; i < 4; ++i){
        const int mm = m + i;
        const size_t grow = ((size_t)(mm >> 11) * 16 + e) * 2048 + (mm & 2047);
        out[grow * H_ + h] = acc[mf][nf][i] + bb;
      }
    }
  }
  #undef G2_STAGE
}

extern "C" void kernel_launch(void* const* d_in, const int* in_sizes, int n_in,
                              void* d_out, int out_size, void* d_ws, size_t ws_size,
                              hipStream_t stream){
  const float *x = nullptr, *b1 = nullptr, *b2 = nullptr;
  const float* w12[2] = {nullptr, nullptr}; int nw = 0;
  for (int i = 0; i < n_in; ++i){
    long sz = (long)in_sizes[i];
    if      (sz == (long)G_ * E_ * C_ * H_) x = (const float*)d_in[i];
    else if (sz == (long)E_ * H_ * F_) { if (nw < 2) w12[nw++] = (const float*)d_in[i]; }
    else if (sz == (long)E_ * F_) b1 = (const float*)d_in[i];
    else if (sz == (long)E_ * H_) b2 = (const float*)d_in[i];
  }
  const float* w1 = w12[0];
  const float* w2 = w12[1];
  if (!x || !w1 || !w2 || !b1 || !b2){
    x  = (const float*)d_in[0];
    w1 = (const float*)d_in[1];
    b1 = (const float*)d_in[2];
    w2 = (const float*)d_in[3];
    b2 = (const float*)d_in[4];
  }

  // ws layout (134 MB total, same footprint as all passing rounds):
  ushort* w1t  = (ushort*)d_ws;                        // [E][F][H] 33.5 MB
  ushort* w2t  = w1t + (size_t)E_ * F_ * H_;           // [E][H][F] 33.5 MB
  ushort* h1a  = w2t + (size_t)E_ * H_ * F_;           // 2 slabs x [8192][2048] 67 MB

  transpose_cvt<<<dim3(F_ / 64, H_ / 64, E_), dim3(256), 0, stream>>>(w1, w1t, H_, F_);
  transpose_cvt<<<dim3(H_ / 64, F_ / 64, E_), dim3(256), 0, stream>>>(w2, w2t, F_, H_);

  for (int e0 = 0; e0 < E_; e0 += 2){
    gemm1_gelu<<<dim3(64, 16), dim3(256), 0, stream>>>(x, b1, w1t,
        h1a,                         e0);
    gemm1_gelu<<<dim3(64, 16), dim3(256), 0, stream>>>(x, b1, w1t,
        h1a + (size_t)8192 * F_,     e0 + 1);
    gemm2<<<dim3(64, 4, 2), dim3(256), 0, stream>>>(h1a, b2, w2t,
        (float*)d_out, e0);
  }
}

// Round 15
// 1061.315 us; speedup vs baseline: 3.3981x; 1.0824x over previous
//
#include <hip/hip_runtime.h>
#include <hip/hip_bf16.h>
#include <stdint.h>

#define G_ 4
#define E_ 16
#define C_ 2048
#define H_ 512
#define F_ 2048

typedef __attribute__((ext_vector_type(8))) short bf16x8;
typedef __attribute__((ext_vector_type(4))) float f32x4;
typedef uint32_t u32_glb __attribute__((address_space(1)));
typedef uint32_t u32_lds __attribute__((address_space(3)));

__device__ __forceinline__ ushort f2bf(float f){
  uint u = __float_as_uint(f);
  return (ushort)((u + 0x7FFFu + ((u >> 16) & 1u)) >> 16);  // RNE
}

__device__ __forceinline__ bf16x8 pack8(f32x4 a, f32x4 b){
  union { bf16x8 v; uint u[4]; } p;
  p.u[0] = (uint)f2bf(a[0]) | ((uint)f2bf(a[1]) << 16);
  p.u[1] = (uint)f2bf(a[2]) | ((uint)f2bf(a[3]) << 16);
  p.u[2] = (uint)f2bf(b[0]) | ((uint)f2bf(b[1]) << 16);
  p.u[3] = (uint)f2bf(b[2]) | ((uint)f2bf(b[3]) << 16);
  return p.v;
}

// fast GELU (R10-validated: absmax 1.95e-3 same as exact-erf version)
__device__ __forceinline__ float geluf(float t){
  float y = 0.7978845608f * t * (1.0f + 0.044715f * t * t);
  y = fminf(fmaxf(y, -9.0f), 9.0f);
  float z = __expf(-2.0f * y);
  return t * __builtin_amdgcn_rcpf(1.0f + z);
}

// transpose + fp32->bf16 convert: src [E][R][C] fp32 -> dst [E][C][R] bf16
__global__ void transpose_cvt(const float* __restrict__ src, ushort* __restrict__ dst,
                              int R, int C){
  __shared__ float tile[64][65];
  int c0 = blockIdx.x * 64, r0 = blockIdx.y * 64, e = blockIdx.z;
  int tx = threadIdx.x & 63, ty = threadIdx.x >> 6;   // 256 threads
  const float* s = src + (size_t)e * R * C;
  #pragma unroll
  for (int it = 0; it < 16; ++it){
    int row = ty + it * 4;
    tile[row][tx] = s[(size_t)(r0 + row) * C + (c0 + tx)];
  }
  __syncthreads();
  ushort* d = dst + (size_t)e * C * R;
  #pragma unroll
  for (int it = 0; it < 16; ++it){
    int row = ty + it * 4;
    d[(size_t)(c0 + row) * R + (r0 + tx)] = f2bf(tile[tx][row]);
  }
}

// ================= device GEMM bodies (R14-validated math, unchanged) =================
// m97 structure: 128x128 tile, BK=32, 256 thr / 4 waves (2x2), 4x4 16x16x32 frags.

__device__ __forceinline__ void dev_gemm1(
    ushort* sA, ushort* sB,             // each [2][128*32] (base ptr)
    const float* __restrict__ x, const float* __restrict__ b1,
    const ushort* __restrict__ w1t, ushort* __restrict__ h1slab,
    int e, int m0, int n0){
  const int tid  = threadIdx.x;
  const int lane = tid & 63;
  const int wv   = tid >> 6;
  const int l15  = lane & 15;
  const int lg   = lane >> 4;
  const int wm   = wv >> 1;
  const int wn   = wv & 1;
  const ushort* w1e = w1t + (size_t)e * F_ * H_;

  f32x4 acc[4][4];
  #pragma unroll
  for (int a = 0; a < 4; ++a)
    #pragma unroll
    for (int b = 0; b < 4; ++b) acc[a][b] = (f32x4){0.f,0.f,0.f,0.f};
  f32x4 ar[4];

  const int arow = tid >> 1, ahf = tid & 1;
  const int an   = m0 + arow;
  const float* asrc = x + (((size_t)(an >> 11) * 16 + e) * 2048 + (an & 2047)) * 512 + ahf * 16;

  #define G1_LOAD_A(KK) {                                                        \
    const float* p = asrc + (KK) * 32;                                           \
    ar[0] = *(const f32x4*)p;       ar[1] = *(const f32x4*)(p + 4);              \
    ar[2] = *(const f32x4*)(p + 8); ar[3] = *(const f32x4*)(p + 12); }
  #define G1_WRITE_A(NB) {                                                       \
    ushort* d = sA + (NB) * 4096 + arow * 32 + ahf * 16;                         \
    *(bf16x8*)d       = pack8(ar[0], ar[1]);                                     \
    *(bf16x8*)(d + 8) = pack8(ar[2], ar[3]); }
  #define G1_STAGE_B(KK, NB) {                                                   \
    _Pragma("unroll")                                                            \
    for (int i = 0; i < 2; ++i){                                                 \
      const ushort* gs = w1e + (size_t)(n0 + wv * 16 + i * 64 + (lane >> 2)) * H_\
                       + (KK) * 32 + (lane & 3) * 8;                             \
      __builtin_amdgcn_global_load_lds((const u32_glb*)(uintptr_t)gs,            \
          (u32_lds*)(uintptr_t)(sB + (NB) * 4096 + (wv * 16 + i * 64) * 32), 16, 0, 0); \
    } }

  G1_LOAD_A(0) G1_STAGE_B(0, 0) G1_WRITE_A(0)
  __syncthreads();

  for (int kk = 0; kk < 16; ++kk){
    const int cur = kk & 1, nxt = cur ^ 1;
    if (kk < 15){ G1_LOAD_A(kk + 1) G1_STAGE_B(kk + 1, nxt) }
    bf16x8 af[4], bfr[4];
    #pragma unroll
    for (int mf = 0; mf < 4; ++mf)
      af[mf] = *(const bf16x8*)(sA + cur * 4096 + (wm * 64 + mf * 16 + l15) * 32 + lg * 8);
    #pragma unroll
    for (int nf = 0; nf < 4; ++nf)
      bfr[nf] = *(const bf16x8*)(sB + cur * 4096 + (wn * 64 + nf * 16 + l15) * 32 + lg * 8);
    __builtin_amdgcn_s_setprio(1);
    #pragma unroll
    for (int mf = 0; mf < 4; ++mf)
      #pragma unroll
      for (int nf = 0; nf < 4; ++nf)
        acc[mf][nf] = __builtin_amdgcn_mfma_f32_16x16x32_bf16(af[mf], bfr[nf], acc[mf][nf], 0, 0, 0);
    __builtin_amdgcn_s_setprio(0);
    if (kk < 15){ G1_WRITE_A(nxt) }
    __syncthreads();
  }

  #pragma unroll
  for (int nf = 0; nf < 4; ++nf){
    const int f  = n0 + wn * 64 + nf * 16 + l15;
    const float bb = b1[e * F_ + f];
    #pragma unroll
    for (int mf = 0; mf < 4; ++mf){
      const int m = m0 + wm * 64 + mf * 16 + lg * 4;
      #pragma unroll
      for (int i = 0; i < 4; ++i)
        h1slab[(size_t)(m + i) * F_ + f] = f2bf(geluf(acc[mf][nf][i] + bb));
    }
  }
  #undef G1_LOAD_A
  #undef G1_WRITE_A
  #undef G1_STAGE_B
}

__device__ __forceinline__ void dev_gemm2(
    ushort* sA, ushort* sB,
    const ushort* __restrict__ ha,     // this expert's h1a slab [8192][2048]
    const float* __restrict__ b2, const ushort* __restrict__ w2t,
    float* __restrict__ out, int e, int m0, int n0){
  const int tid  = threadIdx.x;
  const int lane = tid & 63;
  const int wv   = tid >> 6;
  const int l15  = lane & 15;
  const int lg   = lane >> 4;
  const int wm   = wv >> 1;
  const int wn   = wv & 1;
  const ushort* w2e = w2t + (size_t)e * H_ * F_;

  f32x4 acc[4][4];
  #pragma unroll
  for (int a = 0; a < 4; ++a)
    #pragma unroll
    for (int b = 0; b < 4; ++b) acc[a][b] = (f32x4){0.f,0.f,0.f,0.f};

  #define G2_STAGE(KK, NB)  {                                                    \
    _Pragma("unroll")                                                            \
    for (int i = 0; i < 2; ++i){                                                 \
      const ushort* ga = ha + (size_t)(m0 + wv * 16 + i * 64 + (lane >> 2)) * F_ \
                       + (KK) * 32 + (lane & 3) * 8;                             \
      __builtin_amdgcn_global_load_lds((const u32_glb*)(uintptr_t)ga,            \
          (u32_lds*)(uintptr_t)(sA + (NB) * 4096 + (wv * 16 + i * 64) * 32), 16, 0, 0); \
      const ushort* gb = w2e + (size_t)(n0 + wv * 16 + i * 64 + (lane >> 2)) * F_\
                       + (KK) * 32 + (lane & 3) * 8;                             \
      __builtin_amdgcn_global_load_lds((const u32_glb*)(uintptr_t)gb,            \
          (u32_lds*)(uintptr_t)(sB + (NB) * 4096 + (wv * 16 + i * 64) * 32), 16, 0, 0); \
    } }

  G2_STAGE(0, 0)
  __syncthreads();

  for (int kk = 0; kk < 64; ++kk){
    const int cur = kk & 1, nxt = cur ^ 1;
    if (kk < 63){ G2_STAGE(kk + 1, nxt) }
    bf16x8 af[4], bfr[4];
    #pragma unroll
    for (int mf = 0; mf < 4; ++mf)
      af[mf] = *(const bf16x8*)(sA + cur * 4096 + (wm * 64 + mf * 16 + l15) * 32 + lg * 8);
    #pragma unroll
    for (int nf = 0; nf < 4; ++nf)
      bfr[nf] = *(const bf16x8*)(sB + cur * 4096 + (wn * 64 + nf * 16 + l15) * 32 + lg * 8);
    __builtin_amdgcn_s_setprio(1);
    #pragma unroll
    for (int mf = 0; mf < 4; ++mf)
      #pragma unroll
      for (int nf = 0; nf < 4; ++nf)
        acc[mf][nf] = __builtin_amdgcn_mfma_f32_16x16x32_bf16(af[mf], bfr[nf], acc[mf][nf], 0, 0, 0);
    __builtin_amdgcn_s_setprio(0);
    __syncthreads();
  }

  #pragma unroll
  for (int nf = 0; nf < 4; ++nf){
    const int h  = n0 + wn * 64 + nf * 16 + l15;
    const float bb = b2[e * H_ + h];
    #pragma unroll
    for (int mf = 0; mf < 4; ++mf){
      const int m = m0 + wm * 64 + mf * 16 + lg * 4;
      #pragma unroll
      for (int i = 0; i < 4; ++i){
        const int mm = m + i;
        const size_t grow = ((size_t)(mm >> 11) * 16 + e) * 2048 + (mm & 2047);
        out[grow * H_ + h] = acc[mf][nf][i] + bb;
      }
    }
  }
  #undef G2_STAGE
}

// ================= global wrappers =================
#define SLAB ((size_t)8192 * F_)

__global__ __launch_bounds__(256, 3) void gemm1_gelu(
    const float* __restrict__ x, const float* __restrict__ b1,
    const ushort* __restrict__ w1t, ushort* __restrict__ h1a, int e0){
  __shared__ ushort sA[2 * 4096];
  __shared__ ushort sB[2 * 4096];
  const int z = blockIdx.z;
  dev_gemm1(sA, sB, x, b1, w1t, h1a + (size_t)z * SLAB, e0 + z,
            blockIdx.x * 128, blockIdx.y * 128);
}

__global__ __launch_bounds__(256, 3) void gemm2_k(
    const ushort* __restrict__ h1a, const float* __restrict__ b2,
    const ushort* __restrict__ w2t, float* __restrict__ out, int e0){
  __shared__ ushort sA[2 * 4096];
  __shared__ ushort sB[2 * 4096];
  const int z = blockIdx.z;
  dev_gemm2(sA, sB, h1a + (size_t)z * SLAB, b2, w2t, out, e0 + z,
            blockIdx.x * 128, blockIdx.y * 128);
}

// Combined launch: G2 of pair rd (512 blocks, dispatched first) || G1 of pair wr (2048 blocks)
__global__ __launch_bounds__(256, 3) void g2g1_pair(
    const float* __restrict__ x, const float* __restrict__ b1,
    const float* __restrict__ b2, const ushort* __restrict__ w1t,
    const ushort* __restrict__ w2t, const ushort* __restrict__ h1rd,
    ushort* __restrict__ h1wr, float* __restrict__ out, int e_rd, int e_wr){
  __shared__ ushort sA[2 * 4096];
  __shared__ ushort sB[2 * 4096];
  const int bid = blockIdx.x;
  if (bid < 512){
    const int z = bid >> 8, t = bid & 255;
    dev_gemm2(sA, sB, h1rd + (size_t)z * SLAB, b2, w2t, out, e_rd + z,
              (t & 63) * 128, (t >> 6) * 128);
  } else {
    const int b = bid - 512;
    const int z = b >> 10, t = b & 1023;
    dev_gemm1(sA, sB, x, b1, w1t, h1wr + (size_t)z * SLAB, e_wr + z,
              (t & 63) * 128, (t >> 6) * 128);
  }
}

extern "C" void kernel_launch(void* const* d_in, const int* in_sizes, int n_in,
                              void* d_out, int out_size, void* d_ws, size_t ws_size,
                              hipStream_t stream){
  const float *x = nullptr, *b1 = nullptr, *b2 = nullptr;
  const float* w12[2] = {nullptr, nullptr}; int nw = 0;
  for (int i = 0; i < n_in; ++i){
    long sz = (long)in_sizes[i];
    if      (sz == (long)G_ * E_ * C_ * H_) x = (const float*)d_in[i];
    else if (sz == (long)E_ * H_ * F_) { if (nw < 2) w12[nw++] = (const float*)d_in[i]; }
    else if (sz == (long)E_ * F_) b1 = (const float*)d_in[i];
    else if (sz == (long)E_ * H_) b2 = (const float*)d_in[i];
  }
  const float* w1 = w12[0];
  const float* w2 = w12[1];
  if (!x || !w1 || !w2 || !b1 || !b2){
    x  = (const float*)d_in[0];
    w1 = (const float*)d_in[1];
    b1 = (const float*)d_in[2];
    w2 = (const float*)d_in[3];
    b2 = (const float*)d_in[4];
  }

  ushort* w1t = (ushort*)d_ws;                        // [E][F][H] 33.5 MB
  ushort* w2t = w1t + (size_t)E_ * F_ * H_;           // [E][H][F] 33.5 MB
  ushort* h1a = w2t + (size_t)E_ * H_ * F_;           // slabs
  float*  out = (float*)d_out;

  // how many 33.5 MB h1a slabs fit? (deterministic -> graph-safe)
  const size_t wElems = (size_t)2 * E_ * F_ * H_;
  size_t availE = ws_size / 2;
  int nslab = (availE > wElems) ? (int)((availE - wElems) / SLAB) : 0;

  transpose_cvt<<<dim3(F_ / 64, H_ / 64, E_), dim3(256), 0, stream>>>(w1, w1t, H_, F_);
  transpose_cvt<<<dim3(H_ / 64, F_ / 64, E_), dim3(256), 0, stream>>>(w2, w2t, F_, H_);

  if (nslab >= 16){
    // Path A: 2 big launches
    gemm1_gelu<<<dim3(64, 16, 16), dim3(256), 0, stream>>>(x, b1, w1t, h1a, 0);
    gemm2_k  <<<dim3(64,  4, 16), dim3(256), 0, stream>>>(h1a, b2, w2t, out, 0);
  } else if (nslab >= 4){
    // Path B: software-pipelined combined launches (4 slabs, alternating pairs)
    gemm1_gelu<<<dim3(64, 16, 2), dim3(256), 0, stream>>>(x, b1, w1t, h1a, 0);
    for (int p = 0; p < 7; ++p){
      ushort* rd = h1a + (size_t)(p & 1) * 2 * SLAB;
      ushort* wr = h1a + (size_t)((p + 1) & 1) * 2 * SLAB;
      g2g1_pair<<<dim3(2560), dim3(256), 0, stream>>>(x, b1, b2, w1t, w2t,
                                                      rd, wr, out, 2 * p, 2 * p + 2);
    }
    gemm2_k<<<dim3(64, 4, 2), dim3(256), 0, stream>>>(h1a + (size_t)(7 & 1) * 2 * SLAB,
                                                      b2, w2t, out, 14);
  } else {
    // Path C: pairwise (proven 134 MB footprint)
    for (int e0 = 0; e0 < E_; e0 += 2){
      gemm1_gelu<<<dim3(64, 16, 2), dim3(256), 0, stream>>>(x, b1, w1t, h1a, e0);
      gemm2_k  <<<dim3(64,  4, 2), dim3(256), 0, stream>>>(h1a, b2, w2t, out, e0);
    }
  }
}

// Round 16
// 1012.175 us; speedup vs baseline: 3.5631x; 1.0485x over previous
//
#include <hip/hip_runtime.h>
#include <hip/hip_bf16.h>
#include <stdint.h>

#define G_ 4
#define E_ 16
#define C_ 2048
#define H_ 512
#define F_ 2048

typedef __attribute__((ext_vector_type(8))) short bf16x8;
typedef __attribute__((ext_vector_type(4))) float f32x4;
typedef uint32_t u32_glb __attribute__((address_space(1)));
typedef uint32_t u32_lds __attribute__((address_space(3)));

__device__ __forceinline__ ushort f2bf(float f){
  uint u = __float_as_uint(f);
  return (ushort)((u + 0x7FFFu + ((u >> 16) & 1u)) >> 16);  // RNE
}

__device__ __forceinline__ bf16x8 pack8(f32x4 a, f32x4 b){
  union { bf16x8 v; uint u[4]; } p;
  p.u[0] = (uint)f2bf(a[0]) | ((uint)f2bf(a[1]) << 16);
  p.u[1] = (uint)f2bf(a[2]) | ((uint)f2bf(a[3]) << 16);
  p.u[2] = (uint)f2bf(b[0]) | ((uint)f2bf(b[1]) << 16);
  p.u[3] = (uint)f2bf(b[2]) | ((uint)f2bf(b[3]) << 16);
  return p.v;
}

// fast GELU (R10-validated: absmax 1.95e-3 same as exact-erf version)
__device__ __forceinline__ float geluf(float t){
  float y = 0.7978845608f * t * (1.0f + 0.044715f * t * t);
  y = fminf(fmaxf(y, -9.0f), 9.0f);
  float z = __expf(-2.0f * y);
  return t * __builtin_amdgcn_rcpf(1.0f + z);
}

// transpose + fp32->bf16 convert: src [E][R][C] fp32 -> dst [E][C][R] bf16
__global__ void transpose_cvt(const float* __restrict__ src, ushort* __restrict__ dst,
                              int R, int C){
  __shared__ float tile[64][65];
  int c0 = blockIdx.x * 64, r0 = blockIdx.y * 64, e = blockIdx.z;
  int tx = threadIdx.x & 63, ty = threadIdx.x >> 6;   // 256 threads
  const float* s = src + (size_t)e * R * C;
  #pragma unroll
  for (int it = 0; it < 16; ++it){
    int row = ty + it * 4;
    tile[row][tx] = s[(size_t)(r0 + row) * C + (c0 + tx)];
  }
  __syncthreads();
  ushort* d = dst + (size_t)e * C * R;
  #pragma unroll
  for (int it = 0; it < 16; ++it){
    int row = ty + it * 4;
    d[(size_t)(c0 + row) * R + (r0 + tx)] = f2bf(tile[tx][row]);
  }
}

// X fp32 -> bf16, straight copy (memory-bound, ~65 us)
__global__ __launch_bounds__(256) void cvt_x(const float* __restrict__ x,
                                             ushort* __restrict__ xbf){
  const size_t stride = (size_t)gridDim.x * 256 * 16;
  size_t base = ((size_t)blockIdx.x * 256 + threadIdx.x) * 16;
  for (size_t i = base; i < (size_t)G_ * E_ * C_ * H_; i += stride){
    f32x4 a0 = *(const f32x4*)(x + i);
    f32x4 a1 = *(const f32x4*)(x + i + 4);
    f32x4 a2 = *(const f32x4*)(x + i + 8);
    f32x4 a3 = *(const f32x4*)(x + i + 12);
    *(bf16x8*)(xbf + i)     = pack8(a0, a1);
    *(bf16x8*)(xbf + i + 8) = pack8(a2, a3);
  }
}

// ================= device GEMM bodies (m97 structure) =================
// 128x128 tile, BK=32, 256 thr / 4 waves (2x2), 4x4 16x16x32 frags, both ops DMA.

// GEMM1: h1slab[8192][2048] = gelu(Xe[8192][512] @ w1t_e^T + b1). K = 512 (16 iters).
__device__ __forceinline__ void dev_gemm1(
    ushort* sA, ushort* sB,
    const ushort* __restrict__ xbf, const float* __restrict__ b1,
    const ushort* __restrict__ w1t, ushort* __restrict__ h1slab,
    int e, int m0, int n0){
  const int tid  = threadIdx.x;
  const int lane = tid & 63;
  const int wv   = tid >> 6;
  const int l15  = lane & 15;
  const int lg   = lane >> 4;
  const int wm   = wv >> 1;
  const int wn   = wv & 1;
  const ushort* w1e = w1t + (size_t)e * F_ * H_;
  // X rows for this tile are contiguous: base row = (m0>>11)*16*2048 + e*2048 + (m0&2047)
  const ushort* xe = xbf + (((size_t)(m0 >> 11) * 16 + e) * 2048 + (m0 & 2047)) * H_;

  f32x4 acc[4][4];
  #pragma unroll
  for (int a = 0; a < 4; ++a)
    #pragma unroll
    for (int b = 0; b < 4; ++b) acc[a][b] = (f32x4){0.f,0.f,0.f,0.f};

  #define G1_STAGE(KK, NB) {                                                     \
    _Pragma("unroll")                                                            \
    for (int i = 0; i < 2; ++i){                                                 \
      const int r = wv * 16 + i * 64 + (lane >> 2);                              \
      const ushort* ga = xe + (size_t)r * H_ + (KK) * 32 + (lane & 3) * 8;       \
      __builtin_amdgcn_global_load_lds((const u32_glb*)(uintptr_t)ga,            \
          (u32_lds*)(uintptr_t)(sA + (NB) * 4096 + r * 32), 16, 0, 0);           \
      const ushort* gb = w1e + (size_t)(n0 + r) * H_ + (KK) * 32 + (lane & 3) * 8;\
      __builtin_amdgcn_global_load_lds((const u32_glb*)(uintptr_t)gb,            \
          (u32_lds*)(uintptr_t)(sB + (NB) * 4096 + r * 32), 16, 0, 0);           \
    } }

  G1_STAGE(0, 0)
  __syncthreads();

  for (int kk = 0; kk < 16; ++kk){
    const int cur = kk & 1, nxt = cur ^ 1;
    if (kk < 15){ G1_STAGE(kk + 1, nxt) }
    bf16x8 af[4], bfr[4];
    #pragma unroll
    for (int mf = 0; mf < 4; ++mf)
      af[mf] = *(const bf16x8*)(sA + cur * 4096 + (wm * 64 + mf * 16 + l15) * 32 + lg * 8);
    #pragma unroll
    for (int nf = 0; nf < 4; ++nf)
      bfr[nf] = *(const bf16x8*)(sB + cur * 4096 + (wn * 64 + nf * 16 + l15) * 32 + lg * 8);
    __builtin_amdgcn_s_setprio(1);
    #pragma unroll
    for (int mf = 0; mf < 4; ++mf)
      #pragma unroll
      for (int nf = 0; nf < 4; ++nf)
        acc[mf][nf] = __builtin_amdgcn_mfma_f32_16x16x32_bf16(af[mf], bfr[nf], acc[mf][nf], 0, 0, 0);
    __builtin_amdgcn_s_setprio(0);
    __syncthreads();
  }

  #pragma unroll
  for (int nf = 0; nf < 4; ++nf){
    const int f  = n0 + wn * 64 + nf * 16 + l15;
    const float bb = b1[e * F_ + f];
    #pragma unroll
    for (int mf = 0; mf < 4; ++mf){
      const int m = m0 + wm * 64 + mf * 16 + lg * 4;
      #pragma unroll
      for (int i = 0; i < 4; ++i)
        h1slab[(size_t)(m + i) * F_ + f] = f2bf(geluf(acc[mf][nf][i] + bb));
    }
  }
  #undef G1_STAGE
}

// GEMM2: out_e[8192][512] = h1a_e[8192][2048] @ w2t_e^T + b2. K = 2048 (64 iters).
__device__ __forceinline__ void dev_gemm2(
    ushort* sA, ushort* sB,
    const ushort* __restrict__ ha,
    const float* __restrict__ b2, const ushort* __restrict__ w2t,
    float* __restrict__ out, int e, int m0, int n0){
  const int tid  = threadIdx.x;
  const int lane = tid & 63;
  const int wv   = tid >> 6;
  const int l15  = lane & 15;
  const int lg   = lane >> 4;
  const int wm   = wv >> 1;
  const int wn   = wv & 1;
  const ushort* w2e = w2t + (size_t)e * H_ * F_;

  f32x4 acc[4][4];
  #pragma unroll
  for (int a = 0; a < 4; ++a)
    #pragma unroll
    for (int b = 0; b < 4; ++b) acc[a][b] = (f32x4){0.f,0.f,0.f,0.f};

  #define G2_STAGE(KK, NB)  {                                                    \
    _Pragma("unroll")                                                            \
    for (int i = 0; i < 2; ++i){                                                 \
      const int r = wv * 16 + i * 64 + (lane >> 2);                              \
      const ushort* ga = ha + (size_t)(m0 + r) * F_ + (KK) * 32 + (lane & 3) * 8;\
      __builtin_amdgcn_global_load_lds((const u32_glb*)(uintptr_t)ga,            \
          (u32_lds*)(uintptr_t)(sA + (NB) * 4096 + r * 32), 16, 0, 0);           \
      const ushort* gb = w2e + (size_t)(n0 + r) * F_ + (KK) * 32 + (lane & 3) * 8;\
      __builtin_amdgcn_global_load_lds((const u32_glb*)(uintptr_t)gb,            \
          (u32_lds*)(uintptr_t)(sB + (NB) * 4096 + r * 32), 16, 0, 0);           \
    } }

  G2_STAGE(0, 0)
  __syncthreads();

  for (int kk = 0; kk < 64; ++kk){
    const int cur = kk & 1, nxt = cur ^ 1;
    if (kk < 63){ G2_STAGE(kk + 1, nxt) }
    bf16x8 af[4], bfr[4];
    #pragma unroll
    for (int mf = 0; mf < 4; ++mf)
      af[mf] = *(const bf16x8*)(sA + cur * 4096 + (wm * 64 + mf * 16 + l15) * 32 + lg * 8);
    #pragma unroll
    for (int nf = 0; nf < 4; ++nf)
      bfr[nf] = *(const bf16x8*)(sB + cur * 4096 + (wn * 64 + nf * 16 + l15) * 32 + lg * 8);
    __builtin_amdgcn_s_setprio(1);
    #pragma unroll
    for (int mf = 0; mf < 4; ++mf)
      #pragma unroll
      for (int nf = 0; nf < 4; ++nf)
        acc[mf][nf] = __builtin_amdgcn_mfma_f32_16x16x32_bf16(af[mf], bfr[nf], acc[mf][nf], 0, 0, 0);
    __builtin_amdgcn_s_setprio(0);
    __syncthreads();
  }

  #pragma unroll
  for (int nf = 0; nf < 4; ++nf){
    const int h  = n0 + wn * 64 + nf * 16 + l15;
    const float bb = b2[e * H_ + h];
    #pragma unroll
    for (int mf = 0; mf < 4; ++mf){
      const int m = m0 + wm * 64 + mf * 16 + lg * 4;
      #pragma unroll
      for (int i = 0; i < 4; ++i){
        const int mm = m + i;
        const size_t grow = ((size_t)(mm >> 11) * 16 + e) * 2048 + (mm & 2047);
        out[grow * H_ + h] = acc[mf][nf][i] + bb;
      }
    }
  }
  #undef G2_STAGE
}

// ================= global wrappers =================
#define SLAB ((size_t)8192 * F_)

__global__ __launch_bounds__(256, 3) void gemm1_gelu(
    const ushort* __restrict__ xbf, const float* __restrict__ b1,
    const ushort* __restrict__ w1t, ushort* __restrict__ h1a, int e0){
  __shared__ ushort sA[2 * 4096];
  __shared__ ushort sB[2 * 4096];
  const int z = blockIdx.z;
  dev_gemm1(sA, sB, xbf, b1, w1t, h1a + (size_t)z * SLAB, e0 + z,
            blockIdx.x * 128, blockIdx.y * 128);
}

__global__ __launch_bounds__(256, 3) void gemm2_k(
    const ushort* __restrict__ h1a, const float* __restrict__ b2,
    const ushort* __restrict__ w2t, float* __restrict__ out, int e0){
  __shared__ ushort sA[2 * 4096];
  __shared__ ushort sB[2 * 4096];
  const int z = blockIdx.z;
  dev_gemm2(sA, sB, h1a + (size_t)z * SLAB, b2, w2t, out, e0 + z,
            blockIdx.x * 128, blockIdx.y * 128);
}

extern "C" void kernel_launch(void* const* d_in, const int* in_sizes, int n_in,
                              void* d_out, int out_size, void* d_ws, size_t ws_size,
                              hipStream_t stream){
  const float *x = nullptr, *b1 = nullptr, *b2 = nullptr;
  const float* w12[2] = {nullptr, nullptr}; int nw = 0;
  for (int i = 0; i < n_in; ++i){
    long sz = (long)in_sizes[i];
    if      (sz == (long)G_ * E_ * C_ * H_) x = (const float*)d_in[i];
    else if (sz == (long)E_ * H_ * F_) { if (nw < 2) w12[nw++] = (const float*)d_in[i]; }
    else if (sz == (long)E_ * F_) b1 = (const float*)d_in[i];
    else if (sz == (long)E_ * H_) b2 = (const float*)d_in[i];
  }
  const float* w1 = w12[0];
  const float* w2 = w12[1];
  if (!x || !w1 || !w2 || !b1 || !b2){
    x  = (const float*)d_in[0];
    w1 = (const float*)d_in[1];
    b1 = (const float*)d_in[2];
    w2 = (const float*)d_in[3];
    b2 = (const float*)d_in[4];
  }

  // ws layout: w1t | w2t | xbf | h1a slabs
  ushort* w1t = (ushort*)d_ws;                         // 33.5 MB
  ushort* w2t = w1t + (size_t)E_ * F_ * H_;            // 33.5 MB
  ushort* xbf = w2t + (size_t)E_ * H_ * F_;            // 134 MB
  ushort* h1a = xbf + (size_t)G_ * E_ * C_ * H_;       // slabs
  float*  out = (float*)d_out;

  const size_t fixedE = (size_t)2 * E_ * F_ * H_ + (size_t)G_ * E_ * C_ * H_;
  size_t availE = ws_size / 2;
  int nslab = (availE > fixedE) ? (int)((availE - fixedE) / SLAB) : 0;

  transpose_cvt<<<dim3(F_ / 64, H_ / 64, E_), dim3(256), 0, stream>>>(w1, w1t, H_, F_);
  transpose_cvt<<<dim3(H_ / 64, F_ / 64, E_), dim3(256), 0, stream>>>(w2, w2t, F_, H_);
  cvt_x<<<dim3(2048), dim3(256), 0, stream>>>(x, xbf);

  if (nslab >= 16){
    // Path A: 2 big launches
    gemm1_gelu<<<dim3(64, 16, 16), dim3(256), 0, stream>>>(xbf, b1, w1t, h1a, 0);
    gemm2_k  <<<dim3(64,  4, 16), dim3(256), 0, stream>>>(h1a, b2, w2t, out, 0);
  } else {
    // Path C: pairwise
    for (int e0 = 0; e0 < E_; e0 += 2){
      gemm1_gelu<<<dim3(64, 16, 2), dim3(256), 0, stream>>>(xbf, b1, w1t, h1a, e0);
      gemm2_k  <<<dim3(64,  4, 2), dim3(256), 0, stream>>>(h1a, b2, w2t, out, e0);
    }
  }
}